// Round 7
// baseline (77.118 us; speedup 1.0000x reference)
//
#include <hip/hip_runtime.h>
#include <math.h>

typedef float fx4 __attribute__((ext_vector_type(4)));

// DCT-II 8x8 orthonormal matrix constants (match reference _dct_matrix in f32)
#define A0f 0.35355339059327373f
#define B1f 0.49039264020161522f
#define B3f 0.41573480615127262f
#define B5f 0.27778511650980114f
#define B7f 0.09754516100806412f
#define C2f 0.46193976625564337f
#define C6f 0.19134171618254489f

// y[k] = sum_n D[k][n] x[n]
__device__ __forceinline__ void dct1d(const float x[8], float y[8]) {
    float s0 = x[0] + x[7], s1 = x[1] + x[6], s2 = x[2] + x[5], s3 = x[3] + x[4];
    float d0 = x[0] - x[7], d1 = x[1] - x[6], d2 = x[2] - x[5], d3 = x[3] - x[4];
    y[0] = A0f * ((s0 + s3) + (s1 + s2));
    y[4] = A0f * ((s0 + s3) - (s1 + s2));
    y[2] = C2f * s0 + C6f * s1 - C6f * s2 - C2f * s3;
    y[6] = C6f * s0 - C2f * s1 + C2f * s2 - C6f * s3;
    y[1] = B1f * d0 + B3f * d1 + B5f * d2 + B7f * d3;
    y[3] = B3f * d0 - B7f * d1 - B1f * d2 - B5f * d3;
    y[5] = B5f * d0 - B1f * d1 + B7f * d2 + B3f * d3;
    y[7] = B7f * d0 - B5f * d1 + B3f * d2 - B1f * d3;
}

// x[n] = sum_k D[k][n] y[k]
__device__ __forceinline__ void idct1d(const float y[8], float x[8]) {
    float ea = A0f * (y[0] + y[4]);
    float eb = A0f * (y[0] - y[4]);
    float p0 = C2f * y[2] + C6f * y[6];
    float p1 = C6f * y[2] - C2f * y[6];
    float e0 = ea + p0, e1 = eb + p1, e2 = eb - p1, e3 = ea - p0;
    float o0 = B1f * y[1] + B3f * y[3] + B5f * y[5] + B7f * y[7];
    float o1 = B3f * y[1] - B7f * y[3] - B1f * y[5] - B5f * y[7];
    float o2 = B5f * y[1] - B1f * y[3] + B7f * y[5] + B3f * y[7];
    float o3 = B7f * y[1] - B5f * y[3] + B3f * y[5] - B1f * y[7];
    x[0] = e0 + o0; x[7] = e0 - o0;
    x[1] = e1 + o1; x[6] = e1 - o1;
    x[2] = e2 + o2; x[5] = e2 - o2;
    x[3] = e3 + o3; x[4] = e3 - o3;
}

// 8x8 transpose, one column/row per lane across an aligned 8-lane group.
// (Validated in R4-R6: absmax identical to LDS-scratch version.)
__device__ __forceinline__ void transpose8(float x[8], int p) {
#pragma unroll
    for (int d = 1; d < 8; d <<= 1) {
        const bool up = (p & d) != 0;
#pragma unroll
        for (int i = 0; i < 8; ++i) {
            if ((i & d) == 0) {
                float send = up ? x[i] : x[i | d];
                float recv = __shfl_xor(send, d, 64);
                if (up) x[i] = recv; else x[i | d] = recv;
            }
        }
    }
}

// DCT -> quant -> dequant -> IDCT of one 8x8 block; thread p owns column p.
template<int STRIDE>
__device__ __forceinline__ void proc_block(float* base, const float* __restrict__ tabp, int p) {
    float qt[8];
#pragma unroll
    for (int k = 0; k < 8; ++k)
        qt[k] = fminf(fmaxf(rintf(tabp[(p << 3) + k]), 1.0f), 32767.0f);
    float v0[8];
#pragma unroll
    for (int i = 0; i < 8; ++i) v0[i] = base[i * STRIDE + p];
    float t[8];
    dct1d(v0, t);            // lane p: column p of D*X
    transpose8(t, p);        // lane p: row p
    float cf[8];
    dct1d(t, cf);            // lane p: row p of C = D X D^T
#pragma unroll
    for (int k = 0; k < 8; ++k) cf[k] = rintf(cf[k] / qt[k]) * qt[k];
    float vr[8];
    idct1d(cf, vr);          // lane p: row p of U = C D
    transpose8(vr, p);       // lane p: column p
    float rec[8];
    idct1d(vr, rec);         // lane p: column p of rec = D^T U
#pragma unroll
    for (int i = 0; i < 8; ++i) base[i * STRIDE + p] = rec[i];
}

// R3 skeleton: one 16-row x 64-col tile per 256-thread BLOCK, 2 barriers.
// (This structure measured WRITE=96MB exactly / 36.9us.)  Changes vs R3:
// shuffle transpose (no Tr scratch) + shuffle chroma vertical mean (no Pc)
// -> LDS 18.4KB -> 6.7KB -> 8 blocks/CU (wave cap).
__global__ __launch_bounds__(256) void jpeg_fused(
    const float* __restrict__ x, const float* __restrict__ ytab,
    const float* __restrict__ ctab, float* __restrict__ out)
{
    __shared__ float Yt[16][68];     // Y tile (y-128); stride 68: 16B-aligned, 2-way banks
    __shared__ float Cst[2][8][36];  // subsampled cb/cr (-128), then reconstructed

    const int tid = threadIdx.x;
    const int bid = blockIdx.x;
    const int b   = bid >> 10;       // 1024 tiles per image (64 tile-rows x 16 tile-cols)
    const int t_  = bid & 1023;
    const int y0  = (t_ >> 4) << 4;
    const int x0  = (t_ & 15) << 6;

    const int row = tid >> 4;        // 0..15
    const int c4  = tid & 15;        // float4 column index
    const float* xr = x + (size_t)b * 3145728 + (y0 + row) * 1024 + x0 + (c4 << 2);
    float* outr     = out + (size_t)b * 3145728 + (y0 + row) * 1024 + x0 + (c4 << 2);

    // ---------------- staging: load RGB, convert, Y->LDS, chroma 2x2 mean->LDS
    {
        const fx4 r4 = *(const fx4*)(xr);
        const fx4 g4 = *(const fx4*)(xr + 1048576);
        const fx4 b4 = *(const fx4*)(xr + 2097152);
        fx4 y4; float cb[4], cr[4];
#pragma unroll
        for (int j = 0; j < 4; ++j) {
            float rr = r4[j] * 255.0f;
            float gg = g4[j] * 255.0f;
            float bb = b4[j] * 255.0f;
            y4[j] = (0.299f * rr + 0.587f * gg + 0.114f * bb) - 128.0f;
            cb[j] = -0.168736f * rr - 0.331264f * gg + 0.5f * bb;      // cb-128
            cr[j] = 0.5f * rr - 0.418688f * gg - 0.081312f * bb;       // cr-128
        }
        *(fx4*)&Yt[row][c4 << 2] = y4;
        // horizontal pair sums, then vertical pair via lanes tid, tid^16 (rows 2m,2m+1)
        float sb0 = cb[0] + cb[1], sb1 = cb[2] + cb[3];
        float sr0 = cr[0] + cr[1], sr1 = cr[2] + cr[3];
        sb0 += __shfl_xor(sb0, 16, 64);
        sb1 += __shfl_xor(sb1, 16, 64);
        sr0 += __shfl_xor(sr0, 16, 64);
        sr1 += __shfl_xor(sr1, 16, 64);
        if ((tid & 16) == 0) {
            const int rs = row >> 1;             // subsampled row 0..7
            Cst[0][rs][(c4 << 1)]     = 0.25f * sb0;
            Cst[0][rs][(c4 << 1) + 1] = 0.25f * sb1;
            Cst[1][rs][(c4 << 1)]     = 0.25f * sr0;
            Cst[1][rs][(c4 << 1) + 1] = 0.25f * sr1;
        }
    }
    __syncthreads();

    // ---------------- DCT/quant/IDCT: 24 blocks over 32 8-lane groups (wave 3 idles)
    {
        const int wv  = tid >> 6;
        const int sub = (tid >> 3) & 7;
        const int p   = tid & 7;
        const int blk = (wv << 3) + sub;   // 0..31; 24..31 idle (uniform per wave)
        if (blk < 24) {
            if (blk < 16) {
                float* base = &Yt[(blk >> 3) << 3][(blk & 7) << 3];
                proc_block<68>(base, ytab, p);
            } else {
                float* base = &Cst[(blk - 16) >> 2][0][(blk & 3) << 3];
                proc_block<36>(base, ctab, p);
            }
        }
    }
    __syncthreads();

    // ---------------- upsample chroma, YCbCr->RGB, nontemporal store
    {
        const int rs = row >> 1;
        const fx4 y4 = *(const fx4*)&Yt[row][c4 << 2];
        const float cb0 = Cst[0][rs][(c4 << 1)];
        const float cb1 = Cst[0][rs][(c4 << 1) + 1];
        const float cr0 = Cst[1][rs][(c4 << 1)];
        const float cr1 = Cst[1][rs][(c4 << 1) + 1];
        fx4 R4, G4, B4;
#pragma unroll
        for (int j = 0; j < 4; ++j) {
            float Yv = y4[j] + 128.0f;
            float cb = (j < 2) ? cb0 : cb1;
            float cr = (j < 2) ? cr0 : cr1;
            R4[j] = (Yv + 1.402f * cr) * (1.0f / 255.0f);
            G4[j] = (Yv - 0.344136f * cb - 0.714136f * cr) * (1.0f / 255.0f);
            B4[j] = (Yv + 1.772f * cb) * (1.0f / 255.0f);
        }
        __builtin_nontemporal_store(R4, (fx4*)(outr));
        __builtin_nontemporal_store(G4, (fx4*)(outr + 1048576));
        __builtin_nontemporal_store(B4, (fx4*)(outr + 2097152));
    }
}

extern "C" void kernel_launch(void* const* d_in, const int* in_sizes, int n_in,
                              void* d_out, int out_size, void* d_ws, size_t ws_size,
                              hipStream_t stream) {
    const float* x    = (const float*)d_in[0];
    const float* ytab = (const float*)d_in[1];
    const float* ctab = (const float*)d_in[2];
    float* out = (float*)d_out;
    const int B = in_sizes[0] / 3145728;   // 3*1024*1024 per image
    const int grid = B * 1024;             // one 16x64 tile per block
    jpeg_fused<<<grid, 256, 0, stream>>>(x, ytab, ctab, out);
}

// Round 8
// 67.854 us; speedup vs baseline: 1.1365x; 1.1365x over previous
//
#include <hip/hip_runtime.h>
#include <math.h>

typedef float fx4 __attribute__((ext_vector_type(4)));

// DCT-II 8x8 orthonormal matrix constants (match reference _dct_matrix in f32)
#define A0f 0.35355339059327373f
#define B1f 0.49039264020161522f
#define B3f 0.41573480615127262f
#define B5f 0.27778511650980114f
#define B7f 0.09754516100806412f
#define C2f 0.46193976625564337f
#define C6f 0.19134171618254489f

// y[k] = sum_n D[k][n] x[n]  (even/odd symmetry factorization, exact)
__device__ __forceinline__ void dct1d(const float x[8], float y[8]) {
    float s0 = x[0] + x[7], s1 = x[1] + x[6], s2 = x[2] + x[5], s3 = x[3] + x[4];
    float d0 = x[0] - x[7], d1 = x[1] - x[6], d2 = x[2] - x[5], d3 = x[3] - x[4];
    y[0] = A0f * ((s0 + s3) + (s1 + s2));
    y[4] = A0f * ((s0 + s3) - (s1 + s2));
    y[2] = C2f * s0 + C6f * s1 - C6f * s2 - C2f * s3;
    y[6] = C6f * s0 - C2f * s1 + C2f * s2 - C6f * s3;
    y[1] = B1f * d0 + B3f * d1 + B5f * d2 + B7f * d3;
    y[3] = B3f * d0 - B7f * d1 - B1f * d2 - B5f * d3;
    y[5] = B5f * d0 - B1f * d1 + B7f * d2 + B3f * d3;
    y[7] = B7f * d0 - B5f * d1 + B3f * d2 - B1f * d3;
}

// x[n] = sum_k D[k][n] y[k]
__device__ __forceinline__ void idct1d(const float y[8], float x[8]) {
    float ea = A0f * (y[0] + y[4]);
    float eb = A0f * (y[0] - y[4]);
    float p0 = C2f * y[2] + C6f * y[6];
    float p1 = C6f * y[2] - C2f * y[6];
    float e0 = ea + p0, e1 = eb + p1, e2 = eb - p1, e3 = ea - p0;
    float o0 = B1f * y[1] + B3f * y[3] + B5f * y[5] + B7f * y[7];
    float o1 = B3f * y[1] - B7f * y[3] - B1f * y[5] - B5f * y[7];
    float o2 = B5f * y[1] - B1f * y[3] + B7f * y[5] + B3f * y[7];
    float o3 = B7f * y[1] - B5f * y[3] + B3f * y[5] - B1f * y[7];
    x[0] = e0 + o0; x[7] = e0 - o0;
    x[1] = e1 + o1; x[6] = e1 - o1;
    x[2] = e2 + o2; x[5] = e2 - o2;
    x[3] = e3 + o3; x[4] = e3 - o3;
}

// 8x8 transpose, one column/row per lane across an aligned 8-lane group.
// (Validated R4-R7: absmax identical to LDS-scratch version.)
__device__ __forceinline__ void transpose8(float x[8], int p) {
#pragma unroll
    for (int d = 1; d < 8; d <<= 1) {
        const bool up = (p & d) != 0;
#pragma unroll
        for (int i = 0; i < 8; ++i) {
            if ((i & d) == 0) {
                float send = up ? x[i] : x[i | d];
                float recv = __shfl_xor(send, d, 64);
                if (up) x[i] = recv; else x[i | d] = recv;
            }
        }
    }
}

// R3 kernel verbatim EXCEPT: Tr LDS scratch removed; transposes done via
// shuffle butterfly. Global memory access pattern untouched.
__global__ __launch_bounds__(256) void jpeg_fused(
    const float* __restrict__ x, const float* __restrict__ ytab,
    const float* __restrict__ ctab, float* __restrict__ out)
{
    __shared__ float Yt[16][72];      // Y tile (y-128), stride 72 -> <=2-way banks
    __shared__ float Cst[2][8][40];   // reconstructed subsampled Cb/Cr (written in DCT phase)
    __shared__ float Pc[2][16][33];   // horizontal chroma pair-sums (cb/cr - 128)

    const int tid = threadIdx.x;
    const int bid = blockIdx.x;
    const int b   = bid >> 10;        // 1024 tiles per image (64 rows x 16 cols)
    const int t_  = bid & 1023;
    const int trr = t_ >> 4;          // tile row 0..63
    const int tcc = t_ & 15;          // tile col 0..15
    const int y0  = trr << 4;
    const int x0  = tcc << 6;
    const int imgBase = b * 3145728;  // b*3*1024*1024

    // ---------------- staging: load RGB, color convert, store Y + chroma pair sums
    {
        const int row = tid >> 4;     // 0..15
        const int c4  = tid & 15;     // float4 index
        const int rowOff = (y0 + row) * 1024 + x0 + (c4 << 2);
        const fx4 r4 = *(const fx4*)(x + imgBase + rowOff);
        const fx4 g4 = *(const fx4*)(x + imgBase + 1048576 + rowOff);
        const fx4 b4 = *(const fx4*)(x + imgBase + 2097152 + rowOff);
        float ya[4], cba[4], cra[4];
#pragma unroll
        for (int k = 0; k < 4; ++k) {
            float r = r4[k] * 255.0f;
            float g = g4[k] * 255.0f;
            float bl = b4[k] * 255.0f;
            ya[k]  = (0.299f * r + 0.587f * g + 0.114f * bl) - 128.0f;
            cba[k] = -0.168736f * r - 0.331264f * g + 0.5f * bl;       // cb - 128
            cra[k] = 0.5f * r - 0.418688f * g - 0.081312f * bl;        // cr - 128
        }
#pragma unroll
        for (int k = 0; k < 4; ++k) Yt[row][(c4 << 2) + k] = ya[k];
        Pc[0][row][(c4 << 1)]     = cba[0] + cba[1];
        Pc[0][row][(c4 << 1) + 1] = cba[2] + cba[3];
        Pc[1][row][(c4 << 1)]     = cra[0] + cra[1];
        Pc[1][row][(c4 << 1) + 1] = cra[2] + cra[3];
    }
    __syncthreads();

    // ---------------- DCT -> quantize -> dequantize -> IDCT per 8x8 block
    {
        const int wv  = tid >> 6;
        const int sub = (tid >> 3) & 7;
        const int p   = tid & 7;
        const int blk = (wv << 3) + sub;   // 0..31; 24..31 idle (uniform per wave)
        if (blk < 24) {
            const float* tabp = (blk < 16) ? ytab : ctab;
            // quant table row p (rounded + clipped, matches reference)
            float qt[8];
#pragma unroll
            for (int k = 0; k < 8; ++k)
                qt[k] = fminf(fmaxf(rintf(tabp[(p << 3) + k]), 1.0f), 32767.0f);

            // load column p of block (chroma: fold vertical 2x2 mean from Pc)
            float v0[8];
            float* Xb; int stride;
            if (blk < 16) {
                Xb = &Yt[(blk >> 3) << 3][(blk & 7) << 3]; stride = 72;
#pragma unroll
                for (int i = 0; i < 8; ++i) v0[i] = Xb[i * stride + p];
            } else {
                const int ch = (blk >= 20);
                const int j  = ((blk - 16) & 3) << 3;   // column base 0..24
                Xb = &Cst[ch][0][j]; stride = 40;
#pragma unroll
                for (int i = 0; i < 8; ++i)
                    v0[i] = 0.25f * (Pc[ch][2 * i][j + p] + Pc[ch][2 * i + 1][j + p]);
            }

            // vertical DCT (along rows index i)
            float t[8];
            dct1d(v0, t);            // lane p: column p of D*X
            transpose8(t, p);        // lane p: row p

            // horizontal DCT -> coef row p
            float cf[8];
            dct1d(t, cf);

            // quantize + dequantize (rintf = round half to even, like jnp.round)
#pragma unroll
            for (int k = 0; k < 8; ++k) cf[k] = rintf(cf[k] / qt[k]) * qt[k];

            // horizontal IDCT -> row p of intermediate v
            float vrow[8];
            idct1d(cf, vrow);
            transpose8(vrow, p);     // lane p: column p

            // vertical IDCT -> reconstructed column p
            float rec[8];
            idct1d(vrow, rec);
#pragma unroll
            for (int i = 0; i < 8; ++i) Xb[i * stride + p] = rec[i];
        }
    }
    __syncthreads();

    // ---------------- upsample chroma, YCbCr->RGB, nontemporal store
    {
        const int row  = tid >> 4;
        const int c4   = tid & 15;
        const int srow = row >> 1;
        const float cb0 = Cst[0][srow][(c4 << 1)];
        const float cb1 = Cst[0][srow][(c4 << 1) + 1];
        const float cr0 = Cst[1][srow][(c4 << 1)];
        const float cr1 = Cst[1][srow][(c4 << 1) + 1];
        fx4 R4, G4, B4;
#pragma unroll
        for (int k = 0; k < 4; ++k) {
            float Yv = Yt[row][(c4 << 2) + k] + 128.0f;
            float cb = (k < 2) ? cb0 : cb1;
            float cr = (k < 2) ? cr0 : cr1;
            R4[k] = (Yv + 1.402f * cr) * (1.0f / 255.0f);
            G4[k] = (Yv - 0.344136f * cb - 0.714136f * cr) * (1.0f / 255.0f);
            B4[k] = (Yv + 1.772f * cb) * (1.0f / 255.0f);
        }
        const int rowOff = (y0 + row) * 1024 + x0 + (c4 << 2);
        __builtin_nontemporal_store(R4, (fx4*)(out + imgBase + rowOff));
        __builtin_nontemporal_store(G4, (fx4*)(out + imgBase + 1048576 + rowOff));
        __builtin_nontemporal_store(B4, (fx4*)(out + imgBase + 2097152 + rowOff));
    }
}

extern "C" void kernel_launch(void* const* d_in, const int* in_sizes, int n_in,
                              void* d_out, int out_size, void* d_ws, size_t ws_size,
                              hipStream_t stream) {
    const float* x    = (const float*)d_in[0];
    const float* ytab = (const float*)d_in[1];
    const float* ctab = (const float*)d_in[2];
    float* out = (float*)d_out;
    const int B = in_sizes[0] / 3145728;   // 3*1024*1024 per image
    const int grid = B * 1024;             // 64x16 tiles per image
    jpeg_fused<<<grid, 256, 0, stream>>>(x, ytab, ctab, out);
}

// Round 9
// 37.262 us; speedup vs baseline: 2.0696x; 1.8210x over previous
//
#include <hip/hip_runtime.h>
#include <math.h>

typedef float fx4 __attribute__((ext_vector_type(4)));

// DCT-II 8x8 orthonormal matrix constants (match reference _dct_matrix in f32)
#define A0f 0.35355339059327373f
#define B1f 0.49039264020161522f
#define B3f 0.41573480615127262f
#define B5f 0.27778511650980114f
#define B7f 0.09754516100806412f
#define C2f 0.46193976625564337f
#define C6f 0.19134171618254489f

// y[k] = sum_n D[k][n] x[n]  (even/odd symmetry factorization, exact)
__device__ __forceinline__ void dct1d(const float x[8], float y[8]) {
    float s0 = x[0] + x[7], s1 = x[1] + x[6], s2 = x[2] + x[5], s3 = x[3] + x[4];
    float d0 = x[0] - x[7], d1 = x[1] - x[6], d2 = x[2] - x[5], d3 = x[3] - x[4];
    y[0] = A0f * ((s0 + s3) + (s1 + s2));
    y[4] = A0f * ((s0 + s3) - (s1 + s2));
    y[2] = C2f * s0 + C6f * s1 - C6f * s2 - C2f * s3;
    y[6] = C6f * s0 - C2f * s1 + C2f * s2 - C6f * s3;
    y[1] = B1f * d0 + B3f * d1 + B5f * d2 + B7f * d3;
    y[3] = B3f * d0 - B7f * d1 - B1f * d2 - B5f * d3;
    y[5] = B5f * d0 - B1f * d1 + B7f * d2 + B3f * d3;
    y[7] = B7f * d0 - B5f * d1 + B3f * d2 - B1f * d3;
}

// x[n] = sum_k D[k][n] y[k]
__device__ __forceinline__ void idct1d(const float y[8], float x[8]) {
    float ea = A0f * (y[0] + y[4]);
    float eb = A0f * (y[0] - y[4]);
    float p0 = C2f * y[2] + C6f * y[6];
    float p1 = C6f * y[2] - C2f * y[6];
    float e0 = ea + p0, e1 = eb + p1, e2 = eb - p1, e3 = ea - p0;
    float o0 = B1f * y[1] + B3f * y[3] + B5f * y[5] + B7f * y[7];
    float o1 = B3f * y[1] - B7f * y[3] - B1f * y[5] - B5f * y[7];
    float o2 = B5f * y[1] - B1f * y[3] + B7f * y[5] + B3f * y[7];
    float o3 = B7f * y[1] - B5f * y[3] + B3f * y[5] - B1f * y[7];
    x[0] = e0 + o0; x[7] = e0 - o0;
    x[1] = e1 + o1; x[6] = e1 - o1;
    x[2] = e2 + o2; x[5] = e2 - o2;
    x[3] = e3 + o3; x[4] = e3 - o3;
}

// 8x8 transpose via shfl_xor butterfly, STATIC array indexing only:
// every x[] access has a compile-time index after unroll; runtime 'up'
// only feeds value-selects (v_cndmask), never an indexed store.
// (Rule #20: runtime-indexed array stores demote the array to scratch.)
__device__ __forceinline__ void transpose8(float x[8], int p) {
#pragma unroll
    for (int d = 1; d < 8; d <<= 1) {
        const bool up = (p & d) != 0;
#pragma unroll
        for (int i = 0; i < 8; ++i) {
            if ((i & d) == 0) {
                const int j = i | d;
                const float a = x[i], b = x[j];
                const float send = up ? a : b;
                const float recv = __shfl_xor(send, d, 64);
                x[i] = up ? recv : a;
                x[j] = up ? b : recv;
            }
        }
    }
}

// R3 kernel verbatim EXCEPT: Tr LDS scratch removed; transposes done via
// static-indexed shuffle butterfly. Global memory access pattern untouched.
__global__ __launch_bounds__(256) void jpeg_fused(
    const float* __restrict__ x, const float* __restrict__ ytab,
    const float* __restrict__ ctab, float* __restrict__ out)
{
    __shared__ float Yt[16][72];      // Y tile (y-128), stride 72 -> <=2-way banks
    __shared__ float Cst[2][8][40];   // reconstructed subsampled Cb/Cr (written in DCT phase)
    __shared__ float Pc[2][16][33];   // horizontal chroma pair-sums (cb/cr - 128)

    const int tid = threadIdx.x;
    const int bid = blockIdx.x;
    const int b   = bid >> 10;        // 1024 tiles per image (64 rows x 16 cols)
    const int t_  = bid & 1023;
    const int trr = t_ >> 4;          // tile row 0..63
    const int tcc = t_ & 15;          // tile col 0..15
    const int y0  = trr << 4;
    const int x0  = tcc << 6;
    const int imgBase = b * 3145728;  // b*3*1024*1024

    // ---------------- staging: load RGB, color convert, store Y + chroma pair sums
    {
        const int row = tid >> 4;     // 0..15
        const int c4  = tid & 15;     // float4 index
        const int rowOff = (y0 + row) * 1024 + x0 + (c4 << 2);
        const fx4 r4 = *(const fx4*)(x + imgBase + rowOff);
        const fx4 g4 = *(const fx4*)(x + imgBase + 1048576 + rowOff);
        const fx4 b4 = *(const fx4*)(x + imgBase + 2097152 + rowOff);
        float ya[4], cba[4], cra[4];
#pragma unroll
        for (int k = 0; k < 4; ++k) {
            float r = r4[k] * 255.0f;
            float g = g4[k] * 255.0f;
            float bl = b4[k] * 255.0f;
            ya[k]  = (0.299f * r + 0.587f * g + 0.114f * bl) - 128.0f;
            cba[k] = -0.168736f * r - 0.331264f * g + 0.5f * bl;       // cb - 128
            cra[k] = 0.5f * r - 0.418688f * g - 0.081312f * bl;        // cr - 128
        }
#pragma unroll
        for (int k = 0; k < 4; ++k) Yt[row][(c4 << 2) + k] = ya[k];
        Pc[0][row][(c4 << 1)]     = cba[0] + cba[1];
        Pc[0][row][(c4 << 1) + 1] = cba[2] + cba[3];
        Pc[1][row][(c4 << 1)]     = cra[0] + cra[1];
        Pc[1][row][(c4 << 1) + 1] = cra[2] + cra[3];
    }
    __syncthreads();

    // ---------------- DCT -> quantize -> dequantize -> IDCT per 8x8 block
    {
        const int wv  = tid >> 6;
        const int sub = (tid >> 3) & 7;
        const int p   = tid & 7;
        const int blk = (wv << 3) + sub;   // 0..31; 24..31 idle (uniform per wave)
        if (blk < 24) {
            const float* tabp = (blk < 16) ? ytab : ctab;
            // quant table row p (rounded + clipped, matches reference)
            float qt[8];
#pragma unroll
            for (int k = 0; k < 8; ++k)
                qt[k] = fminf(fmaxf(rintf(tabp[(p << 3) + k]), 1.0f), 32767.0f);

            // load column p of block (chroma: fold vertical 2x2 mean from Pc)
            float v0[8];
            float* Xb; int stride;
            if (blk < 16) {
                Xb = &Yt[(blk >> 3) << 3][(blk & 7) << 3]; stride = 72;
#pragma unroll
                for (int i = 0; i < 8; ++i) v0[i] = Xb[i * stride + p];
            } else {
                const int ch = (blk >= 20);
                const int j  = ((blk - 16) & 3) << 3;   // column base 0..24
                Xb = &Cst[ch][0][j]; stride = 40;
#pragma unroll
                for (int i = 0; i < 8; ++i)
                    v0[i] = 0.25f * (Pc[ch][2 * i][j + p] + Pc[ch][2 * i + 1][j + p]);
            }

            // vertical DCT (along rows index i)
            float t[8];
            dct1d(v0, t);            // lane p: column p of D*X
            transpose8(t, p);        // lane p: row p

            // horizontal DCT -> coef row p
            float cf[8];
            dct1d(t, cf);

            // quantize + dequantize (rintf = round half to even, like jnp.round)
#pragma unroll
            for (int k = 0; k < 8; ++k) cf[k] = rintf(cf[k] / qt[k]) * qt[k];

            // horizontal IDCT -> row p of intermediate v
            float vrow[8];
            idct1d(cf, vrow);
            transpose8(vrow, p);     // lane p: column p

            // vertical IDCT -> reconstructed column p
            float rec[8];
            idct1d(vrow, rec);
#pragma unroll
            for (int i = 0; i < 8; ++i) Xb[i * stride + p] = rec[i];
        }
    }
    __syncthreads();

    // ---------------- upsample chroma, YCbCr->RGB, nontemporal store
    {
        const int row  = tid >> 4;
        const int c4   = tid & 15;
        const int srow = row >> 1;
        const float cb0 = Cst[0][srow][(c4 << 1)];
        const float cb1 = Cst[0][srow][(c4 << 1) + 1];
        const float cr0 = Cst[1][srow][(c4 << 1)];
        const float cr1 = Cst[1][srow][(c4 << 1) + 1];
        fx4 R4, G4, B4;
#pragma unroll
        for (int k = 0; k < 4; ++k) {
            float Yv = Yt[row][(c4 << 2) + k] + 128.0f;
            float cb = (k < 2) ? cb0 : cb1;
            float cr = (k < 2) ? cr0 : cr1;
            R4[k] = (Yv + 1.402f * cr) * (1.0f / 255.0f);
            G4[k] = (Yv - 0.344136f * cb - 0.714136f * cr) * (1.0f / 255.0f);
            B4[k] = (Yv + 1.772f * cb) * (1.0f / 255.0f);
        }
        const int rowOff = (y0 + row) * 1024 + x0 + (c4 << 2);
        __builtin_nontemporal_store(R4, (fx4*)(out + imgBase + rowOff));
        __builtin_nontemporal_store(G4, (fx4*)(out + imgBase + 1048576 + rowOff));
        __builtin_nontemporal_store(B4, (fx4*)(out + imgBase + 2097152 + rowOff));
    }
}

extern "C" void kernel_launch(void* const* d_in, const int* in_sizes, int n_in,
                              void* d_out, int out_size, void* d_ws, size_t ws_size,
                              hipStream_t stream) {
    const float* x    = (const float*)d_in[0];
    const float* ytab = (const float*)d_in[1];
    const float* ctab = (const float*)d_in[2];
    float* out = (float*)d_out;
    const int B = in_sizes[0] / 3145728;   // 3*1024*1024 per image
    const int grid = B * 1024;             // 64x16 tiles per image
    jpeg_fused<<<grid, 256, 0, stream>>>(x, ytab, ctab, out);
}